// Round 8
// baseline (401.236 us; speedup 1.0000x reference)
//
#include <hip/hip_runtime.h>

#define BATCH 1024
#define TSEQ  512
#define DIN   64
#define H     128
#define NCLS  10
#define BM    16
#define NTHREADS 512

typedef _Float16 h16;
typedef __attribute__((ext_vector_type(2))) _Float16 half2v;
typedef __attribute__((ext_vector_type(4))) _Float16 half4v;
typedef __attribute__((ext_vector_type(8))) _Float16 half8v;
typedef __attribute__((ext_vector_type(2))) float f32x2;
typedef __attribute__((ext_vector_type(4))) float f32x4;

// Swizzled staging layout (units: halfs) for a 16-row x K-col fp16 tile.
// chunk(m, kg) = kg*16 + (m ^ (kg&7)); element (m,k) at chunk*8 + (k&7).
// A-frag read: lane(ln,grp) reads chunk(ln, 4s+grp) as one aligned b128;
// 64 distinct chunks per instr -> conflict-free. Writes spread by XOR.
__device__ __forceinline__ int stg_addr(int m, int k) {
    const int kg = k >> 3;
    return (((kg << 4) + (m ^ (kg & 7))) << 3) + (k & 7);
}

#define SCALE_G (-2.8853900817779268f)   /* -2*log2(e): tanh gates */
#define SCALE_S (-1.4426950408889634f)   /* -log2(e):   sigmoid gates */

#define MFMA16(A, B, C) __builtin_amdgcn_mfma_f32_16x16x32_f16((A), (B), (C), 0, 0, 0)

// Persistent LSTM: 64 blocks x 16 batch rows, 8 waves/block.
// Wave w owns gate columns [16w,16w+16) of all 4 gates -> c/h update is
// register-local. Weights in registers as scale-folded fp16 B-fragments.
// Latency-oriented schedule per step:
//   pre-barrier : x-pipeline (xf LDS read, x stage write, x-GEMM(t+1),
//                 global prefetch) -- independent of h(t), drains during
//                 barrier wait + next ds_read latency.
//   post-barrier: ds_read h; k-major g/i/f MFMAs (dep distance 3);
//                 o-chain; fused c-math (overlaps o drain); fused h-math.
// Gate math fused over common denominators (7 trans/element):
//   c' = [c*(1+e_g)(1+e_i) + (1-e_g)(1+e_f)] / [(1+e_g)(1+e_i)(1+e_f)]
//   h  = (1-e_c) / ((1+e_c)(1+e_o)),  e_c = exp2(min(c'*SCALE_G, 126))
__global__ __launch_bounds__(NTHREADS, 2)
void lstm_persist(const float* __restrict__ x,
                  const float* __restrict__ Wgx, const float* __restrict__ Wgh,
                  const float* __restrict__ Wix, const float* __restrict__ Wih,
                  const float* __restrict__ Wfx, const float* __restrict__ Wfh,
                  const float* __restrict__ Wox, const float* __restrict__ Woh,
                  const float* __restrict__ Wph,
                  const float* __restrict__ bg, const float* __restrict__ bi,
                  const float* __restrict__ bfg, const float* __restrict__ bo,
                  const float* __restrict__ bp,
                  float* __restrict__ out)
{
    __shared__ __align__(16) h16 hbuf[2][H * BM];    // 2 x 4KB
    __shared__ __align__(16) h16 xbuf[2][DIN * BM];  // 2 x 2KB

    const int tid  = threadIdx.x;
    const int wave = tid >> 6;
    const int lane = tid & 63;
    const int grp  = lane >> 4;
    const int ln   = lane & 15;
    const int b0   = blockIdx.x * BM;
    const int n    = (wave << 4) + ln;   // gate column 0..127

    // ---- weights -> register B-fragments (fp32 -> fp16, scale folded)
    half8v bx[4][2];
    half8v bh[4][4];
    f32x4  bias_c[4];
    {
        const float* WX[4] = {Wgx, Wix, Wfx, Wox};
        const float* WH[4] = {Wgh, Wih, Wfh, Woh};
        const float* BB[4] = {bg, bi, bfg, bo};
        const float  SC[4] = {SCALE_G, SCALE_S, SCALE_S, SCALE_S};
        #pragma unroll
        for (int G = 0; G < 4; ++G) {
            #pragma unroll
            for (int s = 0; s < 2; ++s) {
                half8v v;
                #pragma unroll
                for (int j = 0; j < 8; ++j)
                    v[j] = (h16)(WX[G][(32*s + 8*grp + j) * H + n] * SC[G]);
                bx[G][s] = v;
            }
            #pragma unroll
            for (int s = 0; s < 4; ++s) {
                half8v v;
                #pragma unroll
                for (int j = 0; j < 8; ++j)
                    v[j] = (h16)(WH[G][(32*s + 8*grp + j) * H + n] * SC[G]);
                bh[G][s] = v;
            }
            const float bb = BB[G][n] * SC[G];
            bias_c[G] = (f32x4){bb, bb, bb, bb};
        }
    }

    // ---- hoisted LDS addresses
    const int ha0 = stg_addr(ln,      8 * grp);
    const int ha1 = stg_addr(ln, 32 + 8 * grp);
    const int ha2 = stg_addr(ln, 64 + 8 * grp);
    const int ha3 = stg_addr(ln, 96 + 8 * grp);
    const int xa0 = ha0;                       // xbuf uses same 16x64 layout
    const int xa1 = ha1;
    int hwr[4];
    #pragma unroll
    for (int r = 0; r < 4; ++r) hwr[r] = stg_addr((grp << 2) + r, n);

    // ---- x stager: ALL 512 threads, 2 floats (8B) each
    const int xm  = tid >> 5;             // row 0..15
    const int xk0 = (tid & 31) << 1;      // k 0,2,...,62
    const int xwr = stg_addr(xm, xk0);    // b32-aligned (xk0 even)
    const float* xrow = x + (size_t)(b0 + xm) * TSEQ * DIN + xk0;

    // ---- prologue: zero h(0); prime accA with bias + x(0)-part;
    //      leave xbuf[0]=x(1), xhold=x(2), xnew=x(3).
    *(half4v*)&hbuf[0][tid << 2] = (half4v)0;
    {
        f32x2 x0 = *(const f32x2*)xrow;
        half2v w; w[0] = (h16)x0[0]; w[1] = (h16)x0[1];
        *(half2v*)&xbuf[0][xwr] = w;
    }
    __syncthreads();

    f32x4 accA[4], accB[4];
    {
        half8v xf0 = *(const half8v*)&xbuf[0][xa0];
        half8v xf1 = *(const half8v*)&xbuf[0][xa1];
        #pragma unroll
        for (int G = 0; G < 4; ++G) {
            accA[G] = MFMA16(xf0, bx[G][0], bias_c[G]);
            accA[G] = MFMA16(xf1, bx[G][1], accA[G]);
        }
    }
    __syncthreads();   // protect xbuf[0] overwrite below

    f32x2 xhold, xnew;
    {
        f32x2 x1 = *(const f32x2*)(xrow + DIN);      // x(1)
        half2v w; w[0] = (h16)x1[0]; w[1] = (h16)x1[1];
        *(half2v*)&xbuf[0][xwr] = w;
        xhold = *(const f32x2*)(xrow + 2 * DIN);     // x(2)
        xnew  = *(const f32x2*)(xrow + 3 * DIN);     // x(3)
    }
    __syncthreads();   // x(1) visible before STEP(0)'s pre-barrier read

    f32x4 cstate = {0.f, 0.f, 0.f, 0.f};

// One LSTM step. ACCC = bias + x(t)-part (primed by previous step's
// x-phase); ACCN receives bias + x(t+1)-part in the PRE-barrier phase.
#define STEP(p_, tcur, ACCC, ACCN)                                              \
  {                                                                             \
    /* ===== x-phase (pre-barrier): independent of h(t) ===== */                \
    half8v xf0 = *(const half8v*)&xbuf[p_][xa0];    /* x(tcur+1) */             \
    half8v xf1 = *(const half8v*)&xbuf[p_][xa1];                                \
    { half2v w; w[0] = (h16)xhold[0]; w[1] = (h16)xhold[1];                     \
      *(half2v*)&xbuf[p_ ^ 1][xwr] = w; }          /* stage x(tcur+2) */        \
    xhold = xnew;                                                               \
    const int tpre = ((tcur) + 4 < TSEQ) ? (tcur) + 4 : TSEQ - 1;               \
    xnew = *(const f32x2*)(xrow + (size_t)tpre * DIN);                          \
    _Pragma("unroll")                                                           \
    for (int G = 0; G < 4; ++G) {                                               \
        ACCN[G] = MFMA16(xf0, bx[G][0], bias_c[G]);                             \
        ACCN[G] = MFMA16(xf1, bx[G][1], ACCN[G]);                               \
    }                                                                           \
    __syncthreads();                                                            \
    /* ===== h-phase ===== */                                                   \
    half8v ah0 = *(const half8v*)&hbuf[p_][ha0];                                \
    half8v ah1 = *(const half8v*)&hbuf[p_][ha1];                                \
    half8v ah2 = *(const half8v*)&hbuf[p_][ha2];                                \
    half8v ah3 = *(const half8v*)&hbuf[p_][ha3];                                \
    /* k-major over g,i,f: same-acc dependency distance = 3 */                  \
    ACCC[0] = MFMA16(ah0, bh[0][0], ACCC[0]);                                   \
    ACCC[1] = MFMA16(ah0, bh[1][0], ACCC[1]);                                   \
    ACCC[2] = MFMA16(ah0, bh[2][0], ACCC[2]);                                   \
    ACCC[0] = MFMA16(ah1, bh[0][1], ACCC[0]);                                   \
    ACCC[1] = MFMA16(ah1, bh[1][1], ACCC[1]);                                   \
    ACCC[2] = MFMA16(ah1, bh[2][1], ACCC[2]);                                   \
    ACCC[0] = MFMA16(ah2, bh[0][2], ACCC[0]);                                   \
    ACCC[1] = MFMA16(ah2, bh[1][2], ACCC[1]);                                   \
    ACCC[2] = MFMA16(ah2, bh[2][2], ACCC[2]);                                   \
    ACCC[0] = MFMA16(ah3, bh[0][3], ACCC[0]);                                   \
    ACCC[1] = MFMA16(ah3, bh[1][3], ACCC[1]);                                   \
    ACCC[2] = MFMA16(ah3, bh[2][3], ACCC[2]);                                   \
    /* o-chain: drains under the c-math below */                                \
    ACCC[3] = MFMA16(ah0, bh[3][0], ACCC[3]);                                   \
    ACCC[3] = MFMA16(ah1, bh[3][1], ACCC[3]);                                   \
    ACCC[3] = MFMA16(ah2, bh[3][2], ACCC[3]);                                   \
    ACCC[3] = MFMA16(ah3, bh[3][3], ACCC[3]);                                   \
    /* fused c update: 3 exp2 + 1 rcp per element */                            \
    f32x4 ycv;                                                                  \
    _Pragma("unroll")                                                           \
    for (int r = 0; r < 4; ++r) {                                               \
        float eg = __builtin_amdgcn_exp2f(ACCC[0][r]);                          \
        float ei = __builtin_amdgcn_exp2f(ACCC[1][r]);                          \
        float ef = __builtin_amdgcn_exp2f(ACCC[2][r]);                          \
        float ag = 1.f + eg;                                                    \
        float ai = 1.f + ei;                                                    \
        float af = 1.f + ef;                                                    \
        float dp  = ag * ai;                                                    \
        float num = __builtin_fmaf(cstate[r], dp, (1.f - eg) * af);             \
        float c   = num * __builtin_amdgcn_rcpf(dp * af);                       \
        cstate[r] = c;                                                          \
        ycv[r] = fminf(c * SCALE_G, 126.f);                                     \
    }                                                                           \
    /* fused h = tanh(c)*sigma(o): 2 exp2 + 1 rcp per element */                \
    h16* hw = hbuf[p_ ^ 1];                                                     \
    _Pragma("unroll")                                                           \
    for (int r = 0; r < 4; ++r) {                                               \
        float ec = __builtin_amdgcn_exp2f(ycv[r]);                              \
        float eo = __builtin_amdgcn_exp2f(ACCC[3][r]);                          \
        float dh = (1.f + ec) * (1.f + eo);                                     \
        float hv = (1.f - ec) * __builtin_amdgcn_rcpf(dh);                      \
        hw[hwr[r]] = (h16)hv;                                                   \
    }                                                                           \
  }

    for (int t = 0; t < TSEQ; t += 2) {
        STEP(0, t,     accA, accB)
        STEP(1, t + 1, accB, accA)
    }
#undef STEP

    __syncthreads();
    // final h is in hbuf[0] (t=511 writes p^1 = 0)
    if (tid < BM * NCLS) {
        const int m = tid / NCLS;
        const int cls = tid - m * NCLS;
        float s = bp[cls];
        #pragma unroll 8
        for (int k = 0; k < H; ++k) {
            float hvv = (float)hbuf[0][stg_addr(m, k)];
            s += hvv * Wph[k * NCLS + cls];
        }
        out[(size_t)(b0 + m) * NCLS + cls] = s;
    }
}

extern "C" void kernel_launch(void* const* d_in, const int* in_sizes, int n_in,
                              void* d_out, int out_size, void* d_ws, size_t ws_size,
                              hipStream_t stream) {
    (void)in_sizes; (void)n_in; (void)d_ws; (void)ws_size; (void)out_size;
    lstm_persist<<<dim3(BATCH / BM), dim3(NTHREADS), 0, stream>>>(
        (const float*)d_in[0],
        (const float*)d_in[1], (const float*)d_in[2],
        (const float*)d_in[3], (const float*)d_in[4],
        (const float*)d_in[5], (const float*)d_in[6],
        (const float*)d_in[7], (const float*)d_in[8],
        (const float*)d_in[9],
        (const float*)d_in[10], (const float*)d_in[11],
        (const float*)d_in[12], (const float*)d_in[13],
        (const float*)d_in[14],
        (float*)d_out);
}